// Round 11
// baseline (303.517 us; speedup 1.0000x reference)
//
#include <hip/hip_runtime.h>
#include <cmath>

// SSIM + L1 image similarity loss, MI355X (gfx950).
// es, ta: fp32 [16,3,512,512]. Output: out[0]=l1_loss, out[1]=ssim_loss.
//
// R11: decoding all rounds, __launch_bounds__(B,N) sets a hard VGPR cap of
// ~256/N on this compiler: (512,6)->40, (256,4)->64, (256,3)->84 -- every
// one BELOW the ~85-95 live set -> forced spill. No hint -> allocator used
// 196 -> 2 waves/SIMD, latency-bound (238us). N=2 -> cap 128: above the
// live set (no spill) AND exactly the LDS-allowed occupancy (35.3KB -> 4
// blocks/CU x 4 waves = 16 waves/CU = 4 waves/SIMD needs VGPR<=128).
// R11 = R10 exactly, plus launch_bounds(256,2). One variable.

constexpr int TILE_W = 64;
constexpr int TILE_H = 48;
constexpr int HALO = 5;
constexpr int WIN  = 11;
constexpr int ROWS_PER_WAVE = TILE_H / 4;            // 12
constexpr int STREAM_ROWS = ROWS_PER_WAVE + WIN - 1; // 22
constexpr int LH   = TILE_H + 2 * HALO;  // 58 staged rows
constexpr int LW   = TILE_W + 2 * HALO;  // 74 staged cols
constexpr int LSTR = 76;                 // LDS row stride (float2 units)
constexpr int IMG  = 512;
constexpr float C1C = 0.01f * 0.01f;
constexpr float C2C = 0.03f * 0.03f;

struct Wnd { float g[WIN]; };

__global__ __launch_bounds__(256, 2) void ssim_main(
    const float* __restrict__ es, const float* __restrict__ ta,
    float2* __restrict__ partials, Wnd w)
{
    __shared__ float2 sS[LH * LSTR];
    __shared__ float2 red[4];

    const int tid = threadIdx.x;
    const int tx0 = blockIdx.x * TILE_W;
    const int ty0 = blockIdx.y * TILE_H;
    const int img = blockIdx.z;
    const float* pe = es + (size_t)img * (IMG * IMG);
    const float* pt = ta + (size_t)img * (IMG * IMG);

    // ---- stage interleaved {e,t} tile (zero-pad outside image) ----
    for (int i = tid; i < LH * LW; i += 256) {
        int r = i / LW;
        int c = i - r * LW;
        int gy = ty0 - HALO + r;
        int gx = tx0 - HALO + c;
        float ev = 0.f, tv = 0.f;
        if (gy >= 0 && gy < IMG && gx >= 0 && gx < IMG) {
            int off = gy * IMG + gx;
            ev = pe[off];
            tv = pt[off];
        }
        sS[r * LSTR + c] = make_float2(ev, tv);
    }
    __syncthreads();

    const int wv = tid >> 6;   // wave id 0..3 -> 12-row segment
    const int ln = tid & 63;   // lane -> column
    const int rbase = wv * ROWS_PER_WAVE;
    const float2* rp = &sS[rbase * LSTR + ln];

    float a0[ROWS_PER_WAVE], a1[ROWS_PER_WAVE], a2[ROWS_PER_WAVE],
          a3[ROWS_PER_WAVE], a4[ROWS_PER_WAVE];
    #pragma unroll
    for (int o = 0; o < ROWS_PER_WAVE; ++o) {
        a0[o]=0.f; a1[o]=0.f; a2[o]=0.f; a3[o]=0.f; a4[o]=0.f;
    }

    #pragma unroll
    for (int rr = 0; rr < STREAM_ROWS; ++rr) {
        // horizontal 11-tap of {e, t, e^2, t^2, e*t} for streamed row rr
        float hm1 = 0.f, hm2 = 0.f, h11 = 0.f, h22 = 0.f, h12 = 0.f;
        #pragma unroll
        for (int k = 0; k < WIN; ++k) {
            float2 v = rp[rr * LSTR + k];   // ds_read_b64, imm offset
            float gk = w.g[k];
            float ge = gk * v.x;
            float gt = gk * v.y;
            hm1 += ge;
            hm2 += gt;
            h11 += ge * v.x;
            h22 += gt * v.y;
            h12 += ge * v.y;
        }

        // vertical scatter: streamed row rr feeds output rows rr-10..rr
        #pragma unroll
        for (int k = 0; k < WIN; ++k) {
            int o = rr - k;
            if (o >= 0 && o < ROWS_PER_WAVE) {
                float gk = w.g[k];
                a0[o] += gk * hm1;
                a1[o] += gk * hm2;
                a2[o] += gk * h11;
                a3[o] += gk * h22;
                a4[o] += gk * h12;
            }
        }
    }

    // ---- epilogue: ssim per pixel + L1, then reduce ----
    float ssim_s = 0.f, l1_s = 0.f;
    #pragma unroll
    for (int o = 0; o < ROWS_PER_WAVE; ++o) {
        if (ty0 + rbase + o < IMG) {       // skip padded rows (last stripe)
            float mu1 = a0[o], mu2 = a1[o];
            float m11 = mu1 * mu1, m22 = mu2 * mu2, m12 = mu1 * mu2;
            float s11 = a2[o] - m11;
            float s22 = a3[o] - m22;
            float s12 = a4[o] - m12;
            float num = (2.f * m12 + C1C) * (2.f * s12 + C2C);
            float den = (m11 + m22 + C1C) * (s11 + s22 + C2C);
            ssim_s += num * __builtin_amdgcn_rcpf(den);

            float2 c = rp[(o + HALO) * LSTR + HALO];  // center {e,t}
            l1_s += fabsf(c.x - c.y);
        }
    }

    // ---- block reduce: wave shfl -> LDS[4] -> thread 0 stores partial ----
    #pragma unroll
    for (int off = 32; off >= 1; off >>= 1) {
        ssim_s += __shfl_xor(ssim_s, off, 64);
        l1_s   += __shfl_xor(l1_s, off, 64);
    }
    if (ln == 0) red[wv] = make_float2(ssim_s, l1_s);
    __syncthreads();
    if (tid == 0) {
        float2 r0 = red[0], r1 = red[1], r2 = red[2], r3 = red[3];
        float2 p = make_float2(r0.x + r1.x + r2.x + r3.x,
                               r0.y + r1.y + r2.y + r3.y);
        int bid = (blockIdx.z * gridDim.y + blockIdx.y) * gridDim.x + blockIdx.x;
        partials[bid] = p;
    }
}

__global__ __launch_bounds__(256) void ssim_reduce(
    const float2* __restrict__ partials, int n, float* __restrict__ out)
{
    __shared__ float2 red[4];
    const int tid = threadIdx.x;
    float ssim_s = 0.f, l1_s = 0.f;
    for (int i = tid; i < n; i += 256) {
        float2 p = partials[i];
        ssim_s += p.x;
        l1_s   += p.y;
    }
    #pragma unroll
    for (int off = 32; off >= 1; off >>= 1) {
        ssim_s += __shfl_xor(ssim_s, off, 64);
        l1_s   += __shfl_xor(l1_s, off, 64);
    }
    if ((tid & 63) == 0) red[tid >> 6] = make_float2(ssim_s, l1_s);
    __syncthreads();
    if (tid == 0) {
        float s = red[0].x + red[1].x + red[2].x + red[3].x;
        float l = red[0].y + red[1].y + red[2].y + red[3].y;
        const float N = 16.f * 3.f * 512.f * 512.f;
        out[0] = 0.15f * (l / N);
        out[1] = 0.85f * 0.5f * (1.f - s / N);
    }
}

extern "C" void kernel_launch(void* const* d_in, const int* in_sizes, int n_in,
                              void* d_out, int out_size, void* d_ws, size_t ws_size,
                              hipStream_t stream)
{
    const float* es = (const float*)d_in[0];
    const float* ta = (const float*)d_in[1];
    float* out = (float*)d_out;
    float2* partials = (float2*)d_ws;

    Wnd w;
    double gd[WIN], sum = 0.0;
    for (int i = 0; i < WIN; ++i) {
        double x = (double)(i - WIN / 2);
        gd[i] = std::exp(-(x * x) / (2.0 * 1.5 * 1.5));
        sum += gd[i];
    }
    for (int i = 0; i < WIN; ++i) w.g[i] = (float)(gd[i] / sum);

    const int nimg = in_sizes[0] / (IMG * IMG);  // 16*3 = 48
    dim3 grid(IMG / TILE_W, (IMG + TILE_H - 1) / TILE_H, nimg);  // 8 x 11 x 48
    const int nblocks = grid.x * grid.y * grid.z;                // 4224
    ssim_main<<<grid, 256, 0, stream>>>(es, ta, partials, w);
    ssim_reduce<<<1, 256, 0, stream>>>(partials, nblocks, out);
}

// Round 12
// 152.579 us; speedup vs baseline: 1.9892x; 1.9892x over previous
//
#include <hip/hip_runtime.h>
#include <cmath>

// SSIM + L1 image similarity loss, MI355X (gfx950).
// es, ta: fp32 [16,3,512,512]. Output: out[0]=l1_loss, out[1]=ssim_loss.
//
// R12: launch_bounds(B,N) = hard VGPR cap 256/N (confirmed 3x). The 12-row
// structure's true live set is >128 (R10: 196 unconstrained; R11: spilled
// at cap 128, 598MB scratch). Map so far: no-spill@196 -> 2 waves/SIMD
// (238us); 12-row@cap128 -> spill (303us); R7 spill@cap64 -> 114us.
// Clean cell: shrink live set BELOW the cap by construction.
//  - 8 rows/wave (TILE_H=32): 40 accumulators, live ~90-110 < 128.
//  - cap (256,2): 4 waves/SIMD allowed, no spill possible if live <= 128.
//  - LDS 42x76x8 = 25.5KB -> VGPR-limited 4 blocks/CU x 4 waves = 16/CU.
//  - cost: vertical redundancy 18/8=2.25x vs 1.83x (~+15% VALU) -- cheap
//    against deleting 1.2GB of scratch churn.

constexpr int TILE_W = 64;
constexpr int TILE_H = 32;
constexpr int HALO = 5;
constexpr int WIN  = 11;
constexpr int ROWS_PER_WAVE = TILE_H / 4;            // 8
constexpr int STREAM_ROWS = ROWS_PER_WAVE + WIN - 1; // 18
constexpr int LH   = TILE_H + 2 * HALO;  // 42 staged rows
constexpr int LW   = TILE_W + 2 * HALO;  // 74 staged cols
constexpr int LSTR = 76;                 // LDS row stride (float2 units)
constexpr int IMG  = 512;
constexpr float C1C = 0.01f * 0.01f;
constexpr float C2C = 0.03f * 0.03f;

struct Wnd { float g[WIN]; };

__global__ __launch_bounds__(256, 2) void ssim_main(
    const float* __restrict__ es, const float* __restrict__ ta,
    float2* __restrict__ partials, Wnd w)
{
    __shared__ float2 sS[LH * LSTR];
    __shared__ float2 red[4];

    const int tid = threadIdx.x;
    const int tx0 = blockIdx.x * TILE_W;
    const int ty0 = blockIdx.y * TILE_H;
    const int img = blockIdx.z;
    const float* pe = es + (size_t)img * (IMG * IMG);
    const float* pt = ta + (size_t)img * (IMG * IMG);

    // ---- stage interleaved {e,t} tile (zero-pad outside image) ----
    for (int i = tid; i < LH * LW; i += 256) {
        int r = i / LW;
        int c = i - r * LW;
        int gy = ty0 - HALO + r;
        int gx = tx0 - HALO + c;
        float ev = 0.f, tv = 0.f;
        if (gy >= 0 && gy < IMG && gx >= 0 && gx < IMG) {
            int off = gy * IMG + gx;
            ev = pe[off];
            tv = pt[off];
        }
        sS[r * LSTR + c] = make_float2(ev, tv);
    }
    __syncthreads();

    const int wv = tid >> 6;   // wave id 0..3 -> 8-row segment
    const int ln = tid & 63;   // lane -> column
    const int rbase = wv * ROWS_PER_WAVE;
    const float2* rp = &sS[rbase * LSTR + ln];

    float a0[ROWS_PER_WAVE], a1[ROWS_PER_WAVE], a2[ROWS_PER_WAVE],
          a3[ROWS_PER_WAVE], a4[ROWS_PER_WAVE];
    #pragma unroll
    for (int o = 0; o < ROWS_PER_WAVE; ++o) {
        a0[o]=0.f; a1[o]=0.f; a2[o]=0.f; a3[o]=0.f; a4[o]=0.f;
    }

    #pragma unroll
    for (int rr = 0; rr < STREAM_ROWS; ++rr) {
        // horizontal 11-tap of {e, t, e^2, t^2, e*t} for streamed row rr
        float hm1 = 0.f, hm2 = 0.f, h11 = 0.f, h22 = 0.f, h12 = 0.f;
        #pragma unroll
        for (int k = 0; k < WIN; ++k) {
            float2 v = rp[rr * LSTR + k];   // ds_read_b64, imm offset
            float gk = w.g[k];
            float ge = gk * v.x;
            float gt = gk * v.y;
            hm1 += ge;
            hm2 += gt;
            h11 += ge * v.x;
            h22 += gt * v.y;
            h12 += ge * v.y;
        }

        // vertical scatter: streamed row rr feeds output rows rr-10..rr
        #pragma unroll
        for (int k = 0; k < WIN; ++k) {
            int o = rr - k;
            if (o >= 0 && o < ROWS_PER_WAVE) {
                float gk = w.g[k];
                a0[o] += gk * hm1;
                a1[o] += gk * hm2;
                a2[o] += gk * h11;
                a3[o] += gk * h22;
                a4[o] += gk * h12;
            }
        }
    }

    // ---- epilogue: ssim per pixel + L1, then reduce ----
    float ssim_s = 0.f, l1_s = 0.f;
    #pragma unroll
    for (int o = 0; o < ROWS_PER_WAVE; ++o) {
        float mu1 = a0[o], mu2 = a1[o];
        float m11 = mu1 * mu1, m22 = mu2 * mu2, m12 = mu1 * mu2;
        float s11 = a2[o] - m11;
        float s22 = a3[o] - m22;
        float s12 = a4[o] - m12;
        float num = (2.f * m12 + C1C) * (2.f * s12 + C2C);
        float den = (m11 + m22 + C1C) * (s11 + s22 + C2C);
        ssim_s += num * __builtin_amdgcn_rcpf(den);

        float2 c = rp[(o + HALO) * LSTR + HALO];  // center {e,t}
        l1_s += fabsf(c.x - c.y);
    }

    // ---- block reduce: wave shfl -> LDS[4] -> thread 0 stores partial ----
    #pragma unroll
    for (int off = 32; off >= 1; off >>= 1) {
        ssim_s += __shfl_xor(ssim_s, off, 64);
        l1_s   += __shfl_xor(l1_s, off, 64);
    }
    if (ln == 0) red[wv] = make_float2(ssim_s, l1_s);
    __syncthreads();
    if (tid == 0) {
        float2 r0 = red[0], r1 = red[1], r2 = red[2], r3 = red[3];
        float2 p = make_float2(r0.x + r1.x + r2.x + r3.x,
                               r0.y + r1.y + r2.y + r3.y);
        int bid = (blockIdx.z * gridDim.y + blockIdx.y) * gridDim.x + blockIdx.x;
        partials[bid] = p;
    }
}

__global__ __launch_bounds__(256) void ssim_reduce(
    const float2* __restrict__ partials, int n, float* __restrict__ out)
{
    __shared__ float2 red[4];
    const int tid = threadIdx.x;
    float ssim_s = 0.f, l1_s = 0.f;
    for (int i = tid; i < n; i += 256) {
        float2 p = partials[i];
        ssim_s += p.x;
        l1_s   += p.y;
    }
    #pragma unroll
    for (int off = 32; off >= 1; off >>= 1) {
        ssim_s += __shfl_xor(ssim_s, off, 64);
        l1_s   += __shfl_xor(l1_s, off, 64);
    }
    if ((tid & 63) == 0) red[tid >> 6] = make_float2(ssim_s, l1_s);
    __syncthreads();
    if (tid == 0) {
        float s = red[0].x + red[1].x + red[2].x + red[3].x;
        float l = red[0].y + red[1].y + red[2].y + red[3].y;
        const float N = 16.f * 3.f * 512.f * 512.f;
        out[0] = 0.15f * (l / N);
        out[1] = 0.85f * 0.5f * (1.f - s / N);
    }
}

extern "C" void kernel_launch(void* const* d_in, const int* in_sizes, int n_in,
                              void* d_out, int out_size, void* d_ws, size_t ws_size,
                              hipStream_t stream)
{
    const float* es = (const float*)d_in[0];
    const float* ta = (const float*)d_in[1];
    float* out = (float*)d_out;
    float2* partials = (float2*)d_ws;

    Wnd w;
    double gd[WIN], sum = 0.0;
    for (int i = 0; i < WIN; ++i) {
        double x = (double)(i - WIN / 2);
        gd[i] = std::exp(-(x * x) / (2.0 * 1.5 * 1.5));
        sum += gd[i];
    }
    for (int i = 0; i < WIN; ++i) w.g[i] = (float)(gd[i] / sum);

    const int nimg = in_sizes[0] / (IMG * IMG);  // 16*3 = 48
    dim3 grid(IMG / TILE_W, IMG / TILE_H, nimg); // 8 x 16 x 48 = 6144 blocks
    const int nblocks = grid.x * grid.y * grid.z;
    ssim_main<<<grid, 256, 0, stream>>>(es, ta, partials, w);
    ssim_reduce<<<1, 256, 0, stream>>>(partials, nblocks, out);
}